// Round 1
// baseline (264.595 us; speedup 1.0000x reference)
//
#include <hip/hip_runtime.h>

// SAR-ADC 4-bit successive-approximation quantizer.
// Element-wise over N = LENGTH*NADC = 12M floats. Memory-bound:
//   read x (48 MB), write q (48 MB) + Q (192 MB)  -> ~46 us at 6.3 TB/s.
//
// Numerics: reference does float32 ops throughout. (Q+1)*0.5 is exactly
// 0.0 or 1.0, so each bit_sum = fl(W[m]*VREF) + subset of fl(W[k]*VR),
// added in the reference's fixed order. __fmul_rn/__fadd_rn prevent FMA
// contraction -> bit-exact thresholds -> bit-exact sign decisions.
// sign(x - b + 1e-30) == (x >= b ? +1 : -1): nonzero diffs are >= ~1e-9
// (both operands on coarse float grids), so DELTA only rescues diff==0.

__global__ __launch_bounds__(256)
void sar_adc_kernel(const float* __restrict__ x, const float* __restrict__ W,
                    float* __restrict__ q_out, float* __restrict__ Q_out, int n)
{
    int e = blockIdx.x * blockDim.x + threadIdx.x;
    if (e >= n) return;

    const float VREF = 0.1125f;   // fl32(1.8/16) == fl32(0.1125)
    const float VR   = 0.1125f;

    // Wave-uniform W loads (compiler lifts to s_load).
    float w0 = W[0], w1 = W[1], w2 = W[2], w3 = W[3], w4 = W[4];
    float w5 = W[5], w6 = W[6], w7 = W[7], w8 = W[8], w9 = W[9];

    // Precompute fl(W[k]*VR) terms (exactly what the reference's
    // (Q+1)*0.5*W[k]*VR evaluates to when the bit is set).
    float wv0 = __fmul_rn(w0, VR);
    float wv1 = __fmul_rn(w1, VR);
    float wv2 = __fmul_rn(w2, VR);
    float wv4 = __fmul_rn(w4, VR);
    float wv5 = __fmul_rn(w5, VR);
    float wv7 = __fmul_rn(w7, VR);

    float xv = x[e];

    // j = 3: bit_sum = W[9]*VREF
    float b3 = __fmul_rn(w9, VREF);
    bool s3 = (xv >= b3);

    // j = 2: W[8]*VREF + (Q3+1)*0.5*W[7]*VR
    float b2 = __fmul_rn(w8, VREF);
    if (s3) b2 = __fadd_rn(b2, wv7);
    bool s2 = (xv >= b2);

    // j = 1: W[6]*VREF + (Q2..)*W[5]*VR + (Q3..)*W[4]*VR   (k=2 then k=3)
    float b1 = __fmul_rn(w6, VREF);
    if (s2) b1 = __fadd_rn(b1, wv5);
    if (s3) b1 = __fadd_rn(b1, wv4);
    bool s1 = (xv >= b1);

    // j = 0: W[3]*VREF + (Q1..)*W[2]*VR + (Q2..)*W[1]*VR + (Q3..)*W[0]*VR
    float b0 = __fmul_rn(w3, VREF);
    if (s1) b0 = __fadd_rn(b0, wv2);
    if (s2) b0 = __fadd_rn(b0, wv1);
    if (s3) b0 = __fadd_rn(b0, wv0);
    bool s0 = (xv >= b0);

    // q = sum_k (Q_k+1)*0.5 * bw_k, bw_k = fl32(0.1125)*2^k (exact scalings)
    const float bw0 = 0.1125f, bw1 = 0.225f, bw2 = 0.45f, bw3 = 0.9f;
    float qv = s0 ? bw0 : 0.0f;
    if (s1) qv = __fadd_rn(qv, bw1);
    if (s2) qv = __fadd_rn(qv, bw2);
    if (s3) qv = __fadd_rn(qv, bw3);

    q_out[e] = qv;

    // Q[e] is 4 contiguous floats -> one float4 store, fully coalesced.
    float4 Qv;
    Qv.x = s0 ? 1.0f : -1.0f;
    Qv.y = s1 ? 1.0f : -1.0f;
    Qv.z = s2 ? 1.0f : -1.0f;
    Qv.w = s3 ? 1.0f : -1.0f;
    reinterpret_cast<float4*>(Q_out)[e] = Qv;
}

extern "C" void kernel_launch(void* const* d_in, const int* in_sizes, int n_in,
                              void* d_out, int out_size, void* d_ws, size_t ws_size,
                              hipStream_t stream)
{
    const float* x = (const float*)d_in[0];   // [500000, 24] f32
    const float* W = (const float*)d_in[1];   // [10] f32
    int n = in_sizes[0];                      // 12,000,000 elements

    float* q = (float*)d_out;                 // [n] f32
    float* Q = (float*)d_out + n;             // [n, 4] f32

    const int block = 256;
    const int grid = (n + block - 1) / block;
    sar_adc_kernel<<<grid, block, 0, stream>>>(x, W, q, Q, n);
}